// Round 3
// baseline (244.589 us; speedup 1.0000x reference)
//
#include <hip/hip_runtime.h>
#include <stdint.h>

#define NN 50000
#define NE 800000
#define NG 64
#define F1 256
#define NNP 50176    // padded node count: 392*128, multiple of 448 and 512
#define NBK 196      // dst buckets (d >> 8), 196*256 >= 50000
#define NBS 392      // src buckets (s >> 7), 392*128 = 50176 >= 50000
#define EPB 2048     // edges per k_bscatter block
#define SCB 391      // ceil(NE / EPB)
#define PCHUNKS 112  // k_poolmm K-chunks
#define PKC 448      // K per chunk = 14 * 32; 112*448 = 50176 exactly
#define ZROWS 192    // zpart rows per chunk: 64 hi + 64 lo + 64 indicator

typedef __bf16 bf16x8 __attribute__((ext_vector_type(8)));
typedef float f32x4 __attribute__((ext_vector_type(4)));

__device__ __forceinline__ float bf2f(unsigned int u) {
  union { float f; unsigned int i; } v; v.i = (u & 0xffffu) << 16; return v.f;
}
__device__ __forceinline__ unsigned short f2bf(float f) {
  union { float f; unsigned int i; } v; v.f = f;
  unsigned int r = v.i + 0x7fffu + ((v.i >> 16) & 1u);
  return (unsigned short)(r >> 16);
}
__device__ __forceinline__ float asf(unsigned int u) {
  union { unsigned int u; float f; } v; v.u = u; return v.f;
}
__device__ __forceinline__ unsigned int asu(float f) {
  union { float f; unsigned int u; } v; v.f = f; return v.u;
}

// ---- K1: dual coarse histograms (dst>>8 and src>>7), LDS-merged ----
__global__ void k_bhist(const int* __restrict__ ei, int* __restrict__ btot_d,
                        int* __restrict__ btot_s) {
  __shared__ int lhd[NBK];
  __shared__ int lhs[NBS];
  for (int i = threadIdx.x; i < NBK; i += 256) lhd[i] = 0;
  for (int i = threadIdx.x; i < NBS; i += 256) lhs[i] = 0;
  __syncthreads();
  for (int e = blockIdx.x * blockDim.x + threadIdx.x; e < NE; e += gridDim.x * blockDim.x) {
    atomicAdd(&lhs[ei[e] >> 7], 1);
    atomicAdd(&lhd[ei[NE + e] >> 8], 1);
  }
  __syncthreads();
  for (int i = threadIdx.x; i < NBK; i += 256) atomicAdd(&btot_d[i], lhd[i]);
  for (int i = threadIdx.x; i < NBS; i += 256) atomicAdd(&btot_s[i], lhs[i]);
}

// ---- K2: scan both bucket-total arrays -> bases/cursors; rowp[NN]=NE ----
__global__ void k_bscan(const int* __restrict__ btot_d, const int* __restrict__ btot_s,
                        int* __restrict__ bbase, int* __restrict__ bcur,
                        int* __restrict__ sbase, int* __restrict__ scur,
                        int* __restrict__ rowp) {
  __shared__ int buf[512];
  int t = threadIdx.x;
  int v = (t < NBK) ? btot_d[t] : 0;
  buf[t] = v;
  __syncthreads();
  for (int off = 1; off < 512; off <<= 1) {
    int o = (t >= off) ? buf[t - off] : 0;
    __syncthreads();
    buf[t] += o;
    __syncthreads();
  }
  if (t < NBK) { bbase[t] = buf[t] - v; bcur[t] = buf[t] - v; }
  if (t == NBK - 1) bbase[NBK] = buf[t];
  __syncthreads();
  int v2 = (t < NBS) ? btot_s[t] : 0;
  buf[t] = v2;
  __syncthreads();
  for (int off = 1; off < 512; off <<= 1) {
    int o = (t >= off) ? buf[t - off] : 0;
    __syncthreads();
    buf[t] += o;
    __syncthreads();
  }
  if (t < NBS) { sbase[t] = buf[t] - v2; scur[t] = buf[t] - v2; }
  if (t == NBS - 1) sbase[NBS] = buf[t];
  if (t == 0) rowp[NN] = NE;
}

// ---- K3: dual scatter: dst-records {s|d<<16, x[s]} and src-records {d|sl<<16} ----
__global__ __launch_bounds__(256) void k_bscatter(
    const int* __restrict__ ei, const float* __restrict__ x,
    int* __restrict__ bcur, int* __restrict__ scur,
    uint2* __restrict__ recs, unsigned int* __restrict__ srecs) {
  __shared__ int lhd[NBK]; __shared__ int gbd[NBK];
  __shared__ int lhs[NBS]; __shared__ int gbs[NBS];
  int b = blockIdx.x, tid = threadIdx.x;
  int e0 = b * EPB;
  for (int i = tid; i < NBK; i += 256) lhd[i] = 0;
  for (int i = tid; i < NBS; i += 256) lhs[i] = 0;
  __syncthreads();
  unsigned int meta[8]; float xv[8]; int lofd[8]; int bkd[8]; int lofs[8]; int bks[8];
#pragma unroll
  for (int i = 0; i < 8; ++i) {
    int e = e0 + i * 256 + tid;
    bkd[i] = -1;
    if (e < NE) {
      int s = ei[e], d = ei[NE + e];
      bkd[i] = d >> 8; bks[i] = s >> 7;
      meta[i] = (unsigned int)s | ((unsigned int)d << 16);  // s,d < 65536
      xv[i] = x[s];
      lofd[i] = atomicAdd(&lhd[bkd[i]], 1);
      lofs[i] = atomicAdd(&lhs[bks[i]], 1);
    }
  }
  __syncthreads();
  for (int i = tid; i < NBK; i += 256) gbd[i] = atomicAdd(&bcur[i], lhd[i]);
  for (int i = tid; i < NBS; i += 256) gbs[i] = atomicAdd(&scur[i], lhs[i]);
  __syncthreads();
#pragma unroll
  for (int i = 0; i < 8; ++i) {
    if (bkd[i] >= 0) {
      recs[gbd[bkd[i]] + lofd[i]] = make_uint2(meta[i], asu(xv[i]));
      unsigned int s = meta[i] & 0xFFFFu, d = meta[i] >> 16;
      srecs[gbs[bks[i]] + lofs[i]] = d | ((s & 127u) << 16);
    }
  }
}

// ---- K4: per-dst-bucket fine CSR + per-node ax + dg table + colx scatter ----
__global__ __launch_bounds__(256) void k_csr(
    const uint2* __restrict__ recs, const int* __restrict__ bbase,
    const float* __restrict__ x, const int* __restrict__ batch,
    int* __restrict__ rowp, float2* __restrict__ ax,
    int* __restrict__ colx, uint2* __restrict__ dg) {
  __shared__ int cnt[256];
  __shared__ int sc[256];
  __shared__ float xs[256];
  int b = blockIdx.x, tid = threadIdx.x;
  int eb = bbase[b], ee = bbase[b + 1];
  cnt[tid] = 0;
  xs[tid] = 0.0f;
  __syncthreads();
  for (int e = eb + tid; e < ee; e += 256) {
    uint2 r = recs[e];
    int dl = (r.x >> 16) & 255;
    atomicAdd(&cnt[dl], 1);
    atomicAdd(&xs[dl], asf(r.y));
  }
  __syncthreads();
  sc[tid] = cnt[tid];
  __syncthreads();
  for (int off = 1; off < 256; off <<= 1) {
    int o = (tid >= off) ? sc[tid - off] : 0;
    __syncthreads();
    sc[tid] += o;
    __syncthreads();
  }
  int excl = sc[tid] - cnt[tid];
  int i = b * 256 + tid;
  float dinv = 1.0f / fmaxf((float)cnt[tid], 1.0f);
  if (i < NN) {
    rowp[i] = eb + excl;
    ax[i] = make_float2(xs[tid] * dinv, x[i]);
    dg[i] = make_uint2(asu(dinv), (unsigned int)batch[i]);
  }
  __syncthreads();
  sc[tid] = excl;  // cursor
  __syncthreads();
  for (int e = eb + tid; e < ee; e += 256) {
    uint2 r = recs[e];
    int dl = (r.x >> 16) & 255;
    int s = r.x & 0xFFFF;
    int slot = atomicAdd(&sc[dl], 1);
    colx[eb + slot] = s;
  }
}

// ---- K5: per-src-bucket wg rows in LDS; emit TRANSPOSED bf16 wgT3 ----
// wgT3[g'][s]: rows 0..63 = bf16(wg) (hi), 64..127 = bf16(wg - hi) (lo),
// 128..191 = indicator bf16(batch[s]==g ? 1 : 0) — 1.0 is bf16-exact, so
// ind @ h1T gives p1 on the matrix pipe. Pad cols (s>=NN): wg rows stay 0
// (no edges); ind rows explicitly 0.
__global__ __launch_bounds__(256) void k_csc(
    const unsigned int* __restrict__ srecs, const int* __restrict__ sbase,
    const uint2* __restrict__ dg, const int* __restrict__ batch,
    unsigned int* __restrict__ wgT3u) {
  __shared__ float wgrow[128 * 65];  // [sl][g], pad 65 to break readout conflicts
  __shared__ int sbt[128];
  int b = blockIdx.x, tid = threadIdx.x;
  for (int i = tid; i < 128 * 65; i += 256) wgrow[i] = 0.0f;
  if (tid < 128) {
    int s = b * 128 + tid;
    sbt[tid] = (s < NN) ? batch[s] : -1;
  }
  __syncthreads();
  int eb = sbase[b], ee = sbase[b + 1];
  for (int e = eb + tid; e < ee; e += 256) {
    unsigned int r = srecs[e];
    int d = r & 0xFFFF;
    int sl = (r >> 16) & 127;
    uint2 t = dg[d];  // {deginv bits, g} — 400KB table, L2-resident
    atomicAdd(&wgrow[sl * 65 + t.y], asf(t.x));
  }
  __syncthreads();
  int s0u = b * 64;  // u32 column base (= b*128 bf16 cols / 2)
  int k = tid & 63;
  for (int rr = 0; rr < 16; ++rr) {
    int g = rr * 4 + (tid >> 6);
    float w0 = wgrow[(2 * k) * 65 + g];
    float w1 = wgrow[(2 * k + 1) * 65 + g];
    unsigned short h0 = f2bf(w0), h1v = f2bf(w1);
    unsigned short l0 = f2bf(w0 - bf2f(h0)), l1 = f2bf(w1 - bf2f(h1v));
    wgT3u[(size_t)g * (NNP / 2) + s0u + k] = (unsigned int)h0 | ((unsigned int)h1v << 16);
    wgT3u[(size_t)(64 + g) * (NNP / 2) + s0u + k] = (unsigned int)l0 | ((unsigned int)l1 << 16);
  }
  int bv0 = sbt[2 * k], bv1 = sbt[2 * k + 1];
  for (int rr = 0; rr < 16; ++rr) {
    int g = rr * 4 + (tid >> 6);
    unsigned int u = ((bv0 == g) ? 0x3F80u : 0u) | ((bv1 == g) ? 0x3F800000u : 0u);
    wgT3u[(size_t)(128 + g) * (NNP / 2) + s0u + k] = u;
  }
}

// ---- per-graph node count via binary search over sorted batch ----
__global__ void k_cnt(const int* __restrict__ batch, int* __restrict__ cnt) {
  int g = threadIdx.x;
  if (g >= NG) return;
  int lo = 0, hi = NN;
  while (lo < hi) { int m = (lo + hi) >> 1; if (batch[m] < g) lo = m + 1; else hi = m; }
  int a = lo;
  lo = 0; hi = NN;
  while (lo < hi) { int m = (lo + hi) >> 1; if (batch[m] < g + 1) lo = m + 1; else hi = m; }
  cnt[g] = lo - a;
}

// ---- materialize edge-ordered (a0,x): coalesced write, small-table gather ----
__global__ void k_axe(const int* __restrict__ colx, const float2* __restrict__ ax,
                      float2* __restrict__ axe) {
  int e = blockIdx.x * blockDim.x + threadIdx.x;
  if (e >= NE) return;
  axe[e] = ax[colx[e]];
}

// ---- wcat[n][k]: k<256 -> Wl1[k][n], else Wr1[k-256][n] ----
__global__ void k_wprep(const float* __restrict__ Wl1, const float* __restrict__ Wr1,
                        unsigned short* __restrict__ wcat) {
  int t = blockIdx.x * blockDim.x + threadIdx.x;
  if (t >= 256 * 512) return;
  int n = t >> 9, k = t & 511;
  float v = (k < 256) ? Wl1[k * 256 + n] : Wr1[(k - 256) * 256 + n];
  wcat[t] = f2bf(v);
}

// ---- layer-1 mean-aggregation: stream edge-ordered axe, low-rank recompute ----
__global__ __launch_bounds__(256) void k_agg2(
    const float2* __restrict__ axe, const int* __restrict__ rowp,
    const float* __restrict__ Wl0, const float* __restrict__ b0,
    const float* __restrict__ Wr0, unsigned short* __restrict__ aggb) {
  int wid = threadIdx.x >> 6, lane = threadIdx.x & 63;
  int gw = blockIdx.x * 4 + wid;
  int tw = gridDim.x * 4;
  float wl[4], wr[4], bb[4];
#pragma unroll
  for (int k = 0; k < 4; ++k) {
    wl[k] = Wl0[lane * 4 + k];
    wr[k] = Wr0[lane * 4 + k];
    bb[k] = b0[lane * 4 + k];
  }
  for (int d = gw; d < NN; d += tw) {
    int beg = rowp[d], end = rowp[d + 1];
    float a[4] = {0.f, 0.f, 0.f, 0.f};
    float c[4] = {0.f, 0.f, 0.f, 0.f};
    int e = beg;
    for (; e + 3 < end; e += 4) {
      float2 v0 = axe[e], v1 = axe[e + 1], v2 = axe[e + 2], v3 = axe[e + 3];
#pragma unroll
      for (int k = 0; k < 4; ++k) {
        a[k] += fmaxf(fmaf(v0.x, wl[k], fmaf(v0.y, wr[k], bb[k])), 0.0f);
        c[k] += fmaxf(fmaf(v1.x, wl[k], fmaf(v1.y, wr[k], bb[k])), 0.0f);
        a[k] += fmaxf(fmaf(v2.x, wl[k], fmaf(v2.y, wr[k], bb[k])), 0.0f);
        c[k] += fmaxf(fmaf(v3.x, wl[k], fmaf(v3.y, wr[k], bb[k])), 0.0f);
      }
    }
    for (; e < end; ++e) {
      float2 v0 = axe[e];
#pragma unroll
      for (int k = 0; k < 4; ++k)
        a[k] += fmaxf(fmaf(v0.x, wl[k], fmaf(v0.y, wr[k], bb[k])), 0.0f);
    }
    float dinv = 1.0f / fmaxf((float)(end - beg), 1.0f);
    uint2 o;
    o.x = (unsigned int)f2bf((a[0] + c[0]) * dinv) | ((unsigned int)f2bf((a[1] + c[1]) * dinv) << 16);
    o.y = (unsigned int)f2bf((a[2] + c[2]) * dinv) | ((unsigned int)f2bf((a[3] + c[3]) * dinv) << 16);
    *(uint2*)(aggb + (size_t)d * F1 + lane * 4) = o;
  }
}

// ---- layer 1 GEMM v3: zero-barrier register-streaming MFMA ----
// Both operands are K-contiguous in global ([node][k], [n][k]) -> MFMA
// fragments (8 consecutive k per lane) are direct 16B global loads; no LDS
// staging, no per-step barriers. h0 half (kt>=8) computed per-lane from ax
// (rank-2) with weights broadcast from a 3KB LDS table. Epilogue: LDS
// transpose -> h1T[f][s] 16B stores. p1 moved to k_poolmm (indicator rows).
#define BM 128
#define BN 128

__global__ __launch_bounds__(256, 2) void k_gemm1(
    const unsigned short* __restrict__ aggb, const float2* __restrict__ ax,
    const unsigned short* __restrict__ wcat,
    const float* __restrict__ Wl0, const float* __restrict__ b0,
    const float* __restrict__ Wr0, const float* __restrict__ b1,
    unsigned short* __restrict__ h1T) {
  __shared__ float wl0s[256], wr0s[256], b0s[256];
  __shared__ unsigned short Ts[128 * 128];  // 32KB transpose buffer
  int bm = blockIdx.x, ct = blockIdx.y;
  int tid = threadIdx.x;
  int wid = tid >> 6, lane = tid & 63;
  int wr = wid >> 1, wc = wid & 1;
  int rc = lane & 15, kh = lane >> 4;
  int r0 = bm * BM;

  wl0s[tid] = Wl0[tid];
  wr0s[tid] = Wr0[tid];
  b0s[tid] = b0[tid];

  int arow[4]; bool aok[4]; float2 axr[4];
#pragma unroll
  for (int mf = 0; mf < 4; ++mf) {
    arow[mf] = r0 + wr * 64 + mf * 16 + rc;
    aok[mf] = arow[mf] < NN;
    axr[mf] = aok[mf] ? ax[arow[mf]] : make_float2(0.f, 0.f);
  }
  __syncthreads();  // weights visible

  const unsigned short* bp = wcat + (size_t)(ct * BN + wc * 64 + rc) * 512 + kh * 8;

  f32x4 acc[4][4] = {};  // acc[nf][mf]: (kh,j) <-> f, rc <-> s
  bf16x8 af[2][4], bf[2][4];

#define LOADB(buf, kt)                                                         \
  do {                                                                         \
    _Pragma("unroll") for (int nf = 0; nf < 4; ++nf)                           \
      bf[buf][nf] = *(const bf16x8*)(bp + nf * 16 * 512 + (kt) * 32);          \
  } while (0)

#define LOADA(buf, kt)                                                         \
  do {                                                                         \
    _Pragma("unroll") for (int mf = 0; mf < 4; ++mf) {                         \
      int4 t_ = make_int4(0, 0, 0, 0);                                         \
      if (aok[mf]) t_ = *(const int4*)(aggb + (size_t)arow[mf] * F1 + (kt) * 32 + kh * 8); \
      af[buf][mf] = *(const bf16x8*)&t_;                                       \
    }                                                                          \
  } while (0)

// h0[row][f] = relu(ax.x*Wl0[f] + ax.y*Wr0[f] + b0[f]) for f-window of kt
#define COMPA(buf, kt)                                                         \
  do {                                                                         \
    int f0_ = ((kt) - 8) * 32 + kh * 8;                                        \
    float4 wla_ = *(const float4*)&wl0s[f0_], wlb_ = *(const float4*)&wl0s[f0_ + 4]; \
    float4 wra_ = *(const float4*)&wr0s[f0_], wrb_ = *(const float4*)&wr0s[f0_ + 4]; \
    float4 ba_ = *(const float4*)&b0s[f0_], bb_ = *(const float4*)&b0s[f0_ + 4]; \
    float wlv_[8] = {wla_.x, wla_.y, wla_.z, wla_.w, wlb_.x, wlb_.y, wlb_.z, wlb_.w}; \
    float wrv_[8] = {wra_.x, wra_.y, wra_.z, wra_.w, wrb_.x, wrb_.y, wrb_.z, wrb_.w}; \
    float bbv_[8] = {ba_.x, ba_.y, ba_.z, ba_.w, bb_.x, bb_.y, bb_.z, bb_.w};  \
    _Pragma("unroll") for (int mf = 0; mf < 4; ++mf) {                         \
      bf16x8 h_;                                                               \
      _Pragma("unroll") for (int q = 0; q < 8; ++q) {                          \
        float v_ = fmaxf(fmaf(axr[mf].x, wlv_[q], fmaf(axr[mf].y, wrv_[q], bbv_[q])), 0.0f); \
        h_[q] = (__bf16)v_;                                                    \
      }                                                                        \
      af[buf][mf] = h_;                                                        \
    }                                                                          \
  } while (0)

  LOADB(0, 0);
  LOADA(0, 0);
#pragma unroll
  for (int kt = 0; kt < 16; ++kt) {
    int cb = kt & 1, nb = (kt + 1) & 1;
    if (kt < 15) {
      LOADB(nb, kt + 1);
      if (kt + 1 < 8) LOADA(nb, kt + 1); else COMPA(nb, kt + 1);
    }
#pragma unroll
    for (int nf = 0; nf < 4; ++nf)
#pragma unroll
      for (int mf = 0; mf < 4; ++mf)
        acc[nf][mf] = __builtin_amdgcn_mfma_f32_16x16x32_bf16(bf[cb][nf], af[cb][mf], acc[nf][mf], 0, 0, 0);
  }
#undef LOADB
#undef LOADA
#undef COMPA

  // ---- epilogue: bias+relu, LDS transpose, coalesced h1T store ----
#pragma unroll
  for (int nf = 0; nf < 4; ++nf) {
    int c0l = wc * 64 + nf * 16 + kh * 4;  // local f base of this fragment
    float4 bbq = *(const float4*)(b1 + ct * BN + c0l);
    float bbv[4] = {bbq.x, bbq.y, bbq.z, bbq.w};
#pragma unroll
    for (int mf = 0; mf < 4; ++mf) {
      int s_loc = wr * 64 + mf * 16 + rc;
#pragma unroll
      for (int j = 0; j < 4; ++j) {
        float v = fmaxf(acc[nf][mf][j] + bbv[j], 0.0f);
        int f_loc = c0l + j;
        Ts[f_loc * 128 + (s_loc ^ ((f_loc & 7) << 3))] = f2bf(v);
      }
    }
  }
  __syncthreads();
  {
    int f_loc = tid >> 1;
    int sh = (tid & 1) * 64;
    size_t rowoff = (size_t)(ct * BN + f_loc) * NNP + (size_t)bm * BM;
#pragma unroll
    for (int q = 0; q < 8; ++q) {
      int s_l = sh + q * 8;
      int4 vv = *(const int4*)&Ts[f_loc * 128 + (s_l ^ ((f_loc & 7) << 3))];
      *(int4*)(h1T + rowoff + s_l) = vv;
    }
  }
}

// ---- pool contraction on the MATRIX pipe: zpart[c][g'][f] over K-chunks ----
// Z'[g'][f] = sum_s wgT3[g'][s] * h1T[f][s]; g' 0..63 hi, 64..127 lo,
// 128..191 indicator (-> p1). Pure-register MFMA streamer: no LDS/barriers.
__global__ __launch_bounds__(512) void k_poolmm(
    const unsigned short* __restrict__ h1T, const unsigned short* __restrict__ wgT3,
    float* __restrict__ zpart) {
  int bid = blockIdx.x;
  int c = bid % PCHUNKS, fh = bid / PCHUNKS;
  int tid = threadIdx.x;
  int w = tid >> 6, lane = tid & 63, rc = lane & 15, kh = lane >> 4;
  size_t soff = (size_t)c * PKC + kh * 8;
  const unsigned short* bp = h1T + (size_t)(fh * 128 + w * 16 + rc) * NNP + soff;
  const unsigned short* ap = wgT3 + (size_t)rc * NNP + soff;
  f32x4 acc[12] = {};
  bf16x8 a0[12], a1[12], bA, bB;
#define PLOADS(da, db, ks)                                                     \
  do {                                                                         \
    db = *(const bf16x8*)(bp + (ks) * 32);                                     \
    _Pragma("unroll") for (int mt = 0; mt < 12; ++mt)                          \
      da[mt] = *(const bf16x8*)(ap + (size_t)mt * 16 * NNP + (ks) * 32);       \
  } while (0)
  PLOADS(a0, bA, 0);
  for (int ks = 0; ks < 14; ks += 2) {
    PLOADS(a1, bB, ks + 1);
#pragma unroll
    for (int mt = 0; mt < 12; ++mt)
      acc[mt] = __builtin_amdgcn_mfma_f32_16x16x32_bf16(a0[mt], bA, acc[mt], 0, 0, 0);
    if (ks + 2 < 14) PLOADS(a0, bA, ks + 2);
#pragma unroll
    for (int mt = 0; mt < 12; ++mt)
      acc[mt] = __builtin_amdgcn_mfma_f32_16x16x32_bf16(a1[mt], bB, acc[mt], 0, 0, 0);
  }
#undef PLOADS
  // D: (kh*4+r) <-> g'-within-tile, rc <-> f-within-wave-slice
  float* zp = zpart + ((size_t)c * ZROWS) * F1 + fh * 128 + w * 16 + rc;
#pragma unroll
  for (int mt = 0; mt < 12; ++mt)
#pragma unroll
    for (int r = 0; r < 4; ++r)
      zp[(size_t)(mt * 16 + kh * 4 + r) * F1] = acc[mt][r];
}

// ---- zpart reduction: z[g][f] = sum_c (hi+lo), p1[g][f] = sum_c ind ----
__global__ void k_zred(const float* __restrict__ zpart, float* __restrict__ z,
                       float* __restrict__ p1) {
  int g = blockIdx.x, q = blockIdx.y, t = threadIdx.x;
  float a = 0.0f, b = 0.0f;
  for (int c = q * 28; c < q * 28 + 28; ++c) {
    const float* base = zpart + (size_t)c * ZROWS * F1;
    a += base[(size_t)g * F1 + t] + base[(size_t)(64 + g) * F1 + t];
    b += base[(size_t)(128 + g) * F1 + t];
  }
  atomicAdd(&z[g * F1 + t], a);
  atomicAdd(&p1[g * F1 + t], b);
}

// ---- final: g = (Z/cnt)@Wl2 + b2 + (P/cnt)@Wr2, then LayerNorm ----
__global__ void k_final(const float* __restrict__ z, const float* __restrict__ p1,
                        const int* __restrict__ cnt,
                        const float* __restrict__ Wl2, const float* __restrict__ b2,
                        const float* __restrict__ Wr2, const float* __restrict__ gamma,
                        const float* __restrict__ beta, float* __restrict__ out) {
  __shared__ float s1[128], s2[128];
  int g = blockIdx.x, j = threadIdx.x;
  float invc = 1.0f / fmaxf((float)cnt[g], 1.0f);
  float acc = 0.0f;
  for (int k = 0; k < 256; ++k) {
    acc += z[g * 256 + k] * Wl2[k * 128 + j] + p1[g * 256 + k] * Wr2[k * 128 + j];
  }
  acc = acc * invc + b2[j];
  s1[j] = acc; s2[j] = acc * acc;
  __syncthreads();
  for (int off = 64; off > 0; off >>= 1) {
    if (j < off) { s1[j] += s1[j + off]; s2[j] += s2[j + off]; }
    __syncthreads();
  }
  float mu = s1[0] / 128.0f;
  float var = s2[0] / 128.0f - mu * mu;
  out[g * 128 + j] = (acc - mu) * rsqrtf(var + 1e-5f) * gamma[j] + beta[j];
}

extern "C" void kernel_launch(void* const* d_in, const int* in_sizes, int n_in,
                              void* d_out, int out_size, void* d_ws, size_t ws_size,
                              hipStream_t stream) {
  const float* x = (const float*)d_in[0];
  const int* ei = (const int*)d_in[1];
  const int* batch = (const int*)d_in[2];
  const float* Wl0 = (const float*)d_in[3];
  const float* b0 = (const float*)d_in[4];
  const float* Wr0 = (const float*)d_in[5];
  const float* Wl1 = (const float*)d_in[6];
  const float* b1 = (const float*)d_in[7];
  const float* Wr1 = (const float*)d_in[8];
  const float* Wl2 = (const float*)d_in[9];
  const float* b2 = (const float*)d_in[10];
  const float* Wr2 = (const float*)d_in[11];
  const float* gamma = (const float*)d_in[12];
  const float* beta = (const float*)d_in[13];
  float* out = (float*)d_out;

  char* p = (char*)d_ws;
  auto alloc = [&](size_t bytes) {
    char* r = p;
    p += (bytes + 511) & ~(size_t)511;
    return r;
  };
  unsigned short* h1T = (unsigned short*)alloc((size_t)F1 * NNP * 2);   // 25.7MB transposed h1
  unsigned short* aggb = (unsigned short*)alloc((size_t)NN * F1 * 2);   // hosts recs+srecs+colx (early), zpart (late)
  float2* axe = (float2*)alloc((size_t)NE * 8);
  int* rowp = (int*)alloc((size_t)(NN + 1) * 4);
  float2* ax = (float2*)alloc((size_t)NN * 8);
  uint2* dg = (uint2*)alloc((size_t)NN * 8);
  int* cnt = (int*)alloc((size_t)NG * 4);
  float* z = (float*)alloc((size_t)NG * F1 * 4);
  float* p1 = (float*)alloc((size_t)NG * F1 * 4);
  unsigned short* wcat = (unsigned short*)alloc((size_t)256 * 512 * 2);
  int* btot_d = (int*)alloc((size_t)NBK * 4);
  int* btot_s = (int*)alloc((size_t)NBS * 4);
  int* bbase = (int*)alloc((size_t)(NBK + 1) * 4);
  int* bcur = (int*)alloc((size_t)NBK * 4);
  int* sbase = (int*)alloc((size_t)(NBS + 1) * 4);
  int* scur = (int*)alloc((size_t)NBS * 4);
  unsigned short* wgT3 = (unsigned short*)alloc((size_t)ZROWS * NNP * 2); // 19.3MB hi/lo/ind bf16
  // Aliasing inside aggb (25.6MB): recs (uint2, 6.4MB @0), srecs (uint, 3.2MB
  // @6.4MB), colx (int, 3.2MB @9.6MB). recs dead after k_csr; srecs dead after
  // k_csc; colx dead after k_axe — all complete before k_agg2 writes aggb.
  // zpart (112*192*256*4 = 22.0MB) aliases aggb after k_gemm1 completes.
  uint2* recs = (uint2*)aggb;
  unsigned int* srecs = (unsigned int*)(aggb + (size_t)NE * 4);
  int* colx = (int*)(aggb + (size_t)NE * 6);
  float* zpart = (float*)aggb;

  hipMemsetAsync(btot_d, 0, (size_t)NBK * 4, stream);
  hipMemsetAsync(btot_s, 0, (size_t)NBS * 4, stream);
  hipMemsetAsync(p1, 0, (size_t)NG * F1 * 4, stream);
  hipMemsetAsync(z, 0, (size_t)NG * F1 * 4, stream);

  k_bhist<<<256, 256, 0, stream>>>(ei, btot_d, btot_s);
  k_bscan<<<1, 512, 0, stream>>>(btot_d, btot_s, bbase, bcur, sbase, scur, rowp);
  k_bscatter<<<SCB, 256, 0, stream>>>(ei, x, bcur, scur, recs, srecs);
  k_csr<<<NBK, 256, 0, stream>>>(recs, bbase, x, batch, rowp, ax, colx, dg);
  k_csc<<<NBS, 256, 0, stream>>>(srecs, sbase, dg, batch, (unsigned int*)wgT3);
  k_cnt<<<1, 64, 0, stream>>>(batch, cnt);
  k_axe<<<(NE + 255) / 256, 256, 0, stream>>>(colx, ax, axe);
  k_wprep<<<(256 * 512 + 255) / 256, 256, 0, stream>>>(Wl1, Wr1, wcat);
  k_agg2<<<2048, 256, 0, stream>>>(axe, rowp, Wl0, b0, Wr0, aggb);
  dim3 gg(392, 2);
  k_gemm1<<<gg, 256, 0, stream>>>(aggb, ax, wcat, Wl0, b0, Wr0, b1, h1T);
  k_poolmm<<<2 * PCHUNKS, 512, 0, stream>>>(h1T, wgT3, zpart);
  dim3 zg(NG, 4);
  k_zred<<<zg, 256, 0, stream>>>(zpart, z, p1);
  k_final<<<NG, 128, 0, stream>>>(z, p1, cnt, Wl2, b2, Wr2, gamma, beta, out);
}

// Round 4
// 222.368 us; speedup vs baseline: 1.0999x; 1.0999x over previous
//
#include <hip/hip_runtime.h>
#include <stdint.h>

#define NN 50000
#define NE 800000
#define NG 64
#define F1 256
#define NNP 50176    // padded node count: 392*128, multiple of 448 and 512
#define NBK 196      // dst buckets (d >> 8), 196*256 >= 50000
#define NBS 392      // src buckets (s >> 7), 392*128 = 50176 >= 50000
#define EPB 2048     // edges per k_bscatter block
#define SCB 391      // ceil(NE / EPB)
#define PCHUNKS 112  // k_poolmm K-chunks
#define PKC 448      // K per chunk = 14 * 32; 112*448 = 50176 exactly
#define ZROWS 192    // zpart rows per chunk: 64 hi + 64 lo + 64 indicator

typedef __bf16 bf16x8 __attribute__((ext_vector_type(8)));
typedef float f32x4 __attribute__((ext_vector_type(4)));

__device__ __forceinline__ float bf2f(unsigned int u) {
  union { float f; unsigned int i; } v; v.i = (u & 0xffffu) << 16; return v.f;
}
__device__ __forceinline__ unsigned short f2bf(float f) {
  union { float f; unsigned int i; } v; v.f = f;
  unsigned int r = v.i + 0x7fffu + ((v.i >> 16) & 1u);
  return (unsigned short)(r >> 16);
}
__device__ __forceinline__ float asf(unsigned int u) {
  union { unsigned int u; float f; } v; v.u = u; return v.f;
}
__device__ __forceinline__ unsigned int asu(float f) {
  union { float f; unsigned int u; } v; v.f = f; return v.u;
}

// ---- K1: dual coarse histograms (dst>>8 and src>>7), LDS-merged ----
__global__ void k_bhist(const int* __restrict__ ei, int* __restrict__ btot_d,
                        int* __restrict__ btot_s) {
  __shared__ int lhd[NBK];
  __shared__ int lhs[NBS];
  for (int i = threadIdx.x; i < NBK; i += 256) lhd[i] = 0;
  for (int i = threadIdx.x; i < NBS; i += 256) lhs[i] = 0;
  __syncthreads();
  for (int e = blockIdx.x * blockDim.x + threadIdx.x; e < NE; e += gridDim.x * blockDim.x) {
    atomicAdd(&lhs[ei[e] >> 7], 1);
    atomicAdd(&lhd[ei[NE + e] >> 8], 1);
  }
  __syncthreads();
  for (int i = threadIdx.x; i < NBK; i += 256) atomicAdd(&btot_d[i], lhd[i]);
  for (int i = threadIdx.x; i < NBS; i += 256) atomicAdd(&btot_s[i], lhs[i]);
}

// ---- K2: scan both bucket-total arrays -> bases/cursors; rowp[NN]=NE ----
__global__ void k_bscan(const int* __restrict__ btot_d, const int* __restrict__ btot_s,
                        int* __restrict__ bbase, int* __restrict__ bcur,
                        int* __restrict__ sbase, int* __restrict__ scur,
                        int* __restrict__ rowp) {
  __shared__ int buf[512];
  int t = threadIdx.x;
  int v = (t < NBK) ? btot_d[t] : 0;
  buf[t] = v;
  __syncthreads();
  for (int off = 1; off < 512; off <<= 1) {
    int o = (t >= off) ? buf[t - off] : 0;
    __syncthreads();
    buf[t] += o;
    __syncthreads();
  }
  if (t < NBK) { bbase[t] = buf[t] - v; bcur[t] = buf[t] - v; }
  if (t == NBK - 1) bbase[NBK] = buf[t];
  __syncthreads();
  int v2 = (t < NBS) ? btot_s[t] : 0;
  buf[t] = v2;
  __syncthreads();
  for (int off = 1; off < 512; off <<= 1) {
    int o = (t >= off) ? buf[t - off] : 0;
    __syncthreads();
    buf[t] += o;
    __syncthreads();
  }
  if (t < NBS) { sbase[t] = buf[t] - v2; scur[t] = buf[t] - v2; }
  if (t == NBS - 1) sbase[NBS] = buf[t];
  if (t == 0) rowp[NN] = NE;
}

// ---- K3: dual scatter: dst-records {s|d<<16, x[s]} and src-records {d|sl<<16} ----
__global__ __launch_bounds__(256) void k_bscatter(
    const int* __restrict__ ei, const float* __restrict__ x,
    int* __restrict__ bcur, int* __restrict__ scur,
    uint2* __restrict__ recs, unsigned int* __restrict__ srecs) {
  __shared__ int lhd[NBK]; __shared__ int gbd[NBK];
  __shared__ int lhs[NBS]; __shared__ int gbs[NBS];
  int b = blockIdx.x, tid = threadIdx.x;
  int e0 = b * EPB;
  for (int i = tid; i < NBK; i += 256) lhd[i] = 0;
  for (int i = tid; i < NBS; i += 256) lhs[i] = 0;
  __syncthreads();
  unsigned int meta[8]; float xv[8]; int lofd[8]; int bkd[8]; int lofs[8]; int bks[8];
#pragma unroll
  for (int i = 0; i < 8; ++i) {
    int e = e0 + i * 256 + tid;
    bkd[i] = -1;
    if (e < NE) {
      int s = ei[e], d = ei[NE + e];
      bkd[i] = d >> 8; bks[i] = s >> 7;
      meta[i] = (unsigned int)s | ((unsigned int)d << 16);  // s,d < 65536
      xv[i] = x[s];
      lofd[i] = atomicAdd(&lhd[bkd[i]], 1);
      lofs[i] = atomicAdd(&lhs[bks[i]], 1);
    }
  }
  __syncthreads();
  for (int i = tid; i < NBK; i += 256) gbd[i] = atomicAdd(&bcur[i], lhd[i]);
  for (int i = tid; i < NBS; i += 256) gbs[i] = atomicAdd(&scur[i], lhs[i]);
  __syncthreads();
#pragma unroll
  for (int i = 0; i < 8; ++i) {
    if (bkd[i] >= 0) {
      recs[gbd[bkd[i]] + lofd[i]] = make_uint2(meta[i], asu(xv[i]));
      unsigned int s = meta[i] & 0xFFFFu, d = meta[i] >> 16;
      srecs[gbs[bks[i]] + lofs[i]] = d | ((s & 127u) << 16);
    }
  }
}

// ---- K4: per-dst-bucket fine CSR + per-node ax + dg table + colx scatter ----
__global__ __launch_bounds__(256) void k_csr(
    const uint2* __restrict__ recs, const int* __restrict__ bbase,
    const float* __restrict__ x, const int* __restrict__ batch,
    int* __restrict__ rowp, float2* __restrict__ ax,
    int* __restrict__ colx, uint2* __restrict__ dg) {
  __shared__ int cnt[256];
  __shared__ int sc[256];
  __shared__ float xs[256];
  int b = blockIdx.x, tid = threadIdx.x;
  int eb = bbase[b], ee = bbase[b + 1];
  cnt[tid] = 0;
  xs[tid] = 0.0f;
  __syncthreads();
  for (int e = eb + tid; e < ee; e += 256) {
    uint2 r = recs[e];
    int dl = (r.x >> 16) & 255;
    atomicAdd(&cnt[dl], 1);
    atomicAdd(&xs[dl], asf(r.y));
  }
  __syncthreads();
  sc[tid] = cnt[tid];
  __syncthreads();
  for (int off = 1; off < 256; off <<= 1) {
    int o = (tid >= off) ? sc[tid - off] : 0;
    __syncthreads();
    sc[tid] += o;
    __syncthreads();
  }
  int excl = sc[tid] - cnt[tid];
  int i = b * 256 + tid;
  float dinv = 1.0f / fmaxf((float)cnt[tid], 1.0f);
  if (i < NN) {
    rowp[i] = eb + excl;
    ax[i] = make_float2(xs[tid] * dinv, x[i]);
    dg[i] = make_uint2(asu(dinv), (unsigned int)batch[i]);
  }
  __syncthreads();
  sc[tid] = excl;  // cursor
  __syncthreads();
  for (int e = eb + tid; e < ee; e += 256) {
    uint2 r = recs[e];
    int dl = (r.x >> 16) & 255;
    int s = r.x & 0xFFFF;
    int slot = atomicAdd(&sc[dl], 1);
    colx[eb + slot] = s;
  }
}

// ---- K5: per-src-bucket wg rows in LDS; emit TRANSPOSED bf16 wgT3 ----
// wgT3[g'][s]: rows 0..63 = bf16(wg) (hi), 64..127 = bf16(wg - hi) (lo),
// 128..191 = indicator bf16(batch[s]==g ? 1 : 0) — 1.0 is bf16-exact, so
// ind @ h1T gives p1 on the matrix pipe. Pad cols (s>=NN): all rows 0.
__global__ __launch_bounds__(256) void k_csc(
    const unsigned int* __restrict__ srecs, const int* __restrict__ sbase,
    const uint2* __restrict__ dg, const int* __restrict__ batch,
    unsigned int* __restrict__ wgT3u) {
  __shared__ float wgrow[128 * 65];  // [sl][g], pad 65 to break readout conflicts
  __shared__ int sbt[128];
  int b = blockIdx.x, tid = threadIdx.x;
  for (int i = tid; i < 128 * 65; i += 256) wgrow[i] = 0.0f;
  if (tid < 128) {
    int s = b * 128 + tid;
    sbt[tid] = (s < NN) ? batch[s] : -1;
  }
  __syncthreads();
  int eb = sbase[b], ee = sbase[b + 1];
  for (int e = eb + tid; e < ee; e += 256) {
    unsigned int r = srecs[e];
    int d = r & 0xFFFF;
    int sl = (r >> 16) & 127;
    uint2 t = dg[d];  // {deginv bits, g} — 400KB table, L2-resident
    atomicAdd(&wgrow[sl * 65 + t.y], asf(t.x));
  }
  __syncthreads();
  int s0u = b * 64;  // u32 column base (= b*128 bf16 cols / 2)
  int k = tid & 63;
  for (int rr = 0; rr < 16; ++rr) {
    int g = rr * 4 + (tid >> 6);
    float w0 = wgrow[(2 * k) * 65 + g];
    float w1 = wgrow[(2 * k + 1) * 65 + g];
    unsigned short h0 = f2bf(w0), h1v = f2bf(w1);
    unsigned short l0 = f2bf(w0 - bf2f(h0)), l1 = f2bf(w1 - bf2f(h1v));
    wgT3u[(size_t)g * (NNP / 2) + s0u + k] = (unsigned int)h0 | ((unsigned int)h1v << 16);
    wgT3u[(size_t)(64 + g) * (NNP / 2) + s0u + k] = (unsigned int)l0 | ((unsigned int)l1 << 16);
  }
  int bv0 = sbt[2 * k], bv1 = sbt[2 * k + 1];
  for (int rr = 0; rr < 16; ++rr) {
    int g = rr * 4 + (tid >> 6);
    unsigned int u = ((bv0 == g) ? 0x3F80u : 0u) | ((bv1 == g) ? 0x3F800000u : 0u);
    wgT3u[(size_t)(128 + g) * (NNP / 2) + s0u + k] = u;
  }
}

// ---- per-graph node count via binary search over sorted batch ----
__global__ void k_cnt(const int* __restrict__ batch, int* __restrict__ cnt) {
  int g = threadIdx.x;
  if (g >= NG) return;
  int lo = 0, hi = NN;
  while (lo < hi) { int m = (lo + hi) >> 1; if (batch[m] < g) lo = m + 1; else hi = m; }
  int a = lo;
  lo = 0; hi = NN;
  while (lo < hi) { int m = (lo + hi) >> 1; if (batch[m] < g + 1) lo = m + 1; else hi = m; }
  cnt[g] = lo - a;
}

// ---- materialize edge-ordered (a0,x): coalesced write, small-table gather ----
__global__ void k_axe(const int* __restrict__ colx, const float2* __restrict__ ax,
                      float2* __restrict__ axe) {
  int e = blockIdx.x * blockDim.x + threadIdx.x;
  if (e >= NE) return;
  axe[e] = ax[colx[e]];
}

// ---- wcat[n][k]: k<256 -> Wl1[k][n], else Wr1[k-256][n] ----
__global__ void k_wprep(const float* __restrict__ Wl1, const float* __restrict__ Wr1,
                        unsigned short* __restrict__ wcat) {
  int t = blockIdx.x * blockDim.x + threadIdx.x;
  if (t >= 256 * 512) return;
  int n = t >> 9, k = t & 511;
  float v = (k < 256) ? Wl1[k * 256 + n] : Wr1[(k - 256) * 256 + n];
  wcat[t] = f2bf(v);
}

// ---- layer-1 mean-aggregation: stream edge-ordered axe, low-rank recompute ----
__global__ __launch_bounds__(256) void k_agg2(
    const float2* __restrict__ axe, const int* __restrict__ rowp,
    const float* __restrict__ Wl0, const float* __restrict__ b0,
    const float* __restrict__ Wr0, unsigned short* __restrict__ aggb) {
  int wid = threadIdx.x >> 6, lane = threadIdx.x & 63;
  int gw = blockIdx.x * 4 + wid;
  int tw = gridDim.x * 4;
  float wl[4], wr[4], bb[4];
#pragma unroll
  for (int k = 0; k < 4; ++k) {
    wl[k] = Wl0[lane * 4 + k];
    wr[k] = Wr0[lane * 4 + k];
    bb[k] = b0[lane * 4 + k];
  }
  for (int d = gw; d < NN; d += tw) {
    int beg = rowp[d], end = rowp[d + 1];
    float a[4] = {0.f, 0.f, 0.f, 0.f};
    float c[4] = {0.f, 0.f, 0.f, 0.f};
    int e = beg;
    for (; e + 3 < end; e += 4) {
      float2 v0 = axe[e], v1 = axe[e + 1], v2 = axe[e + 2], v3 = axe[e + 3];
#pragma unroll
      for (int k = 0; k < 4; ++k) {
        a[k] += fmaxf(fmaf(v0.x, wl[k], fmaf(v0.y, wr[k], bb[k])), 0.0f);
        c[k] += fmaxf(fmaf(v1.x, wl[k], fmaf(v1.y, wr[k], bb[k])), 0.0f);
        a[k] += fmaxf(fmaf(v2.x, wl[k], fmaf(v2.y, wr[k], bb[k])), 0.0f);
        c[k] += fmaxf(fmaf(v3.x, wl[k], fmaf(v3.y, wr[k], bb[k])), 0.0f);
      }
    }
    for (; e < end; ++e) {
      float2 v0 = axe[e];
#pragma unroll
      for (int k = 0; k < 4; ++k)
        a[k] += fmaxf(fmaf(v0.x, wl[k], fmaf(v0.y, wr[k], bb[k])), 0.0f);
    }
    float dinv = 1.0f / fmaxf((float)(end - beg), 1.0f);
    uint2 o;
    o.x = (unsigned int)f2bf((a[0] + c[0]) * dinv) | ((unsigned int)f2bf((a[1] + c[1]) * dinv) << 16);
    o.y = (unsigned int)f2bf((a[2] + c[2]) * dinv) | ((unsigned int)f2bf((a[3] + c[3]) * dinv) << 16);
    *(uint2*)(aggb + (size_t)d * F1 + lane * 4) = o;
  }
}

// ---- layer 1 GEMM (R1 structure): LDS double-buffer BK=32, fused h0 ----
// Loop is the measured-fastest variant (<42.8us in R1). Epilogue changed to
// write h1T[f][s] DIRECTLY: unswapped mfma(af,bfr) puts 4 consecutive s per
// lane (rows kh*4+j) at fixed f (col rc) -> 8B uint2 stores, no LDS transpose.
// Grid bm=392 covers padded rows: pad h1 rows = relu(b1) (finite), and wgT3
// pad cols are 0, so pads contribute nothing downstream.
#define BM 128
#define BN 128
#define BK 32

__global__ __launch_bounds__(256) void k_gemm1(
    const unsigned short* __restrict__ aggb, const float2* __restrict__ ax,
    const unsigned short* __restrict__ wcat,
    const float* __restrict__ Wl0, const float* __restrict__ b0,
    const float* __restrict__ Wr0, const float* __restrict__ b1,
    unsigned short* __restrict__ h1T) {
  __shared__ unsigned short As[2][BM][BK];
  __shared__ unsigned short Bs[2][BN][BK];
  __shared__ float wl0s[256], wr0s[256], b0s[256];
  int bm = blockIdx.x, ct = blockIdx.y;
  int tid = threadIdx.x;
  int wid = tid >> 6, lane = tid & 63;
  int wr = wid >> 1, wc = wid & 1;
  int rc = lane & 15, kh = lane >> 4;
  int r0 = bm * BM;
  int srow = tid >> 1;   // 0..127: one staged row per thread
  int sslot = tid & 1;   // which 32B half of the 64B k-row

  wl0s[tid] = Wl0[tid];
  wr0s[tid] = Wr0[tid];
  b0s[tid] = b0[tid];

  int rA = r0 + srow;
  bool rAok = rA < NN;
  float2 axv = rAok ? ax[rA] : make_float2(0.f, 0.f);

  f32x4 acc[4][4] = {};  // acc[mf][nf]: rows (kh,j) <-> s, col rc <-> f
  int4 ra0, ra1, rb0, rb1;

#define LOAD_A(kt)                                                             \
  do {                                                                         \
    ra0 = make_int4(0, 0, 0, 0); ra1 = make_int4(0, 0, 0, 0);                  \
    if (rAok) {                                                                \
      const int4* s_ = (const int4*)(aggb + (size_t)rA * F1 + (kt) * BK + sslot * 16); \
      ra0 = s_[0]; ra1 = s_[1];                                                \
    }                                                                          \
  } while (0)

#define LOAD_B(kt)                                                             \
  do {                                                                         \
    const int4* t_ = (const int4*)(wcat + (size_t)(ct * BN + srow) * 512 + (kt) * BK + sslot * 16); \
    rb0 = t_[0]; rb1 = t_[1];                                                  \
  } while (0)

// h0[rA][j] = relu(ax.x*Wl0[j] + ax.y*Wr0[j] + b0[j]) — bit-identical to old k_h0
#define COMP_A(kt)                                                             \
  do {                                                                         \
    int j0_ = ((kt) - 8) * BK + sslot * 16;                                    \
    unsigned int w_[8];                                                        \
    _Pragma("unroll") for (int q = 0; q < 8; ++q) {                            \
      int j_ = j0_ + 2 * q;                                                    \
      float f0_ = fmaxf(fmaf(axv.x, wl0s[j_], fmaf(axv.y, wr0s[j_], b0s[j_])), 0.0f); \
      float f1_ = fmaxf(fmaf(axv.x, wl0s[j_ + 1], fmaf(axv.y, wr0s[j_ + 1], b0s[j_ + 1])), 0.0f); \
      w_[q] = (unsigned int)f2bf(f0_) | ((unsigned int)f2bf(f1_) << 16);       \
    }                                                                          \
    ra0 = make_int4(w_[0], w_[1], w_[2], w_[3]);                               \
    ra1 = make_int4(w_[4], w_[5], w_[6], w_[7]);                               \
  } while (0)

// swizzle: 4 16B slots/row, phys = logical ^ ((row>>1)&3) -> 2-way (free) on read
#define WRITE_AB(buf)                                                          \
  do {                                                                         \
    int sw_ = (srow >> 1) & 3;                                                 \
    int ws0_ = (2 * sslot) ^ sw_;                                              \
    int ws1_ = (2 * sslot + 1) ^ sw_;                                          \
    *(int4*)&As[buf][srow][ws0_ * 8] = ra0;                                    \
    *(int4*)&As[buf][srow][ws1_ * 8] = ra1;                                    \
    *(int4*)&Bs[buf][srow][ws0_ * 8] = rb0;                                    \
    *(int4*)&Bs[buf][srow][ws1_ * 8] = rb1;                                    \
  } while (0)

  LOAD_B(0);
  LOAD_A(0);
  WRITE_AB(0);
  __syncthreads();
  int cur = 0;
  for (int kt = 0; kt < 16; ++kt) {
    if (kt < 15) {
      LOAD_B(kt + 1);
      if (kt + 1 < 8) LOAD_A(kt + 1);
    }
    bf16x8 af[4], bfr[4];
#pragma unroll
    for (int mf = 0; mf < 4; ++mf) {
      int row = wr * 64 + mf * 16 + rc;
      int sl = kh ^ ((row >> 1) & 3);
      af[mf] = *(const bf16x8*)&As[cur][row][sl * 8];
    }
#pragma unroll
    for (int nf = 0; nf < 4; ++nf) {
      int row = wc * 64 + nf * 16 + rc;
      int sl = kh ^ ((row >> 1) & 3);
      bfr[nf] = *(const bf16x8*)&Bs[cur][row][sl * 8];
    }
#pragma unroll
    for (int mf = 0; mf < 4; ++mf)
#pragma unroll
      for (int nf = 0; nf < 4; ++nf)
        acc[mf][nf] = __builtin_amdgcn_mfma_f32_16x16x32_bf16(af[mf], bfr[nf], acc[mf][nf], 0, 0, 0);
    if (kt < 15) {
      if (kt + 1 >= 8) COMP_A(kt + 1);
      WRITE_AB(cur ^ 1);
    }
    __syncthreads();
    cur ^= 1;
  }
#undef LOAD_A
#undef LOAD_B
#undef COMP_A
#undef WRITE_AB

  // ---- epilogue: bias+relu, direct h1T[f][s] 8B stores ----
  // lane holds s = base + kh*4 + j (4 consecutive) at f = cbase + rc.
#pragma unroll
  for (int nf = 0; nf < 4; ++nf) {
    int f = ct * BN + wc * 64 + nf * 16 + rc;
    float bias = b1[f];
    size_t frow = (size_t)f * NNP;
#pragma unroll
    for (int mf = 0; mf < 4; ++mf) {
      int s0 = r0 + wr * 64 + mf * 16 + kh * 4;
      f32x4 a = acc[mf][nf];
      unsigned int lo = (unsigned int)f2bf(fmaxf(a[0] + bias, 0.0f)) |
                        ((unsigned int)f2bf(fmaxf(a[1] + bias, 0.0f)) << 16);
      unsigned int hi = (unsigned int)f2bf(fmaxf(a[2] + bias, 0.0f)) |
                        ((unsigned int)f2bf(fmaxf(a[3] + bias, 0.0f)) << 16);
      *(uint2*)(h1T + frow + s0) = make_uint2(lo, hi);
    }
  }
}

// ---- pool contraction on the MATRIX pipe: zpart[c][g'][f] over K-chunks ----
// Z'[g'][f] = sum_s wgT3[g'][s] * h1T[f][s]; g' 0..63 hi, 64..127 lo,
// 128..191 indicator (-> p1). Pure-register MFMA streamer: no LDS/barriers.
__global__ __launch_bounds__(512) void k_poolmm(
    const unsigned short* __restrict__ h1T, const unsigned short* __restrict__ wgT3,
    float* __restrict__ zpart) {
  int bid = blockIdx.x;
  int c = bid % PCHUNKS, fh = bid / PCHUNKS;
  int tid = threadIdx.x;
  int w = tid >> 6, lane = tid & 63, rc = lane & 15, kh = lane >> 4;
  size_t soff = (size_t)c * PKC + kh * 8;
  const unsigned short* bp = h1T + (size_t)(fh * 128 + w * 16 + rc) * NNP + soff;
  const unsigned short* ap = wgT3 + (size_t)rc * NNP + soff;
  f32x4 acc[12] = {};
  bf16x8 a0[12], a1[12], bA, bB;
#define PLOADS(da, db, ks)                                                     \
  do {                                                                         \
    db = *(const bf16x8*)(bp + (ks) * 32);                                     \
    _Pragma("unroll") for (int mt = 0; mt < 12; ++mt)                          \
      da[mt] = *(const bf16x8*)(ap + (size_t)mt * 16 * NNP + (ks) * 32);       \
  } while (0)
  PLOADS(a0, bA, 0);
  for (int ks = 0; ks < 14; ks += 2) {
    PLOADS(a1, bB, ks + 1);
#pragma unroll
    for (int mt = 0; mt < 12; ++mt)
      acc[mt] = __builtin_amdgcn_mfma_f32_16x16x32_bf16(a0[mt], bA, acc[mt], 0, 0, 0);
    if (ks + 2 < 14) PLOADS(a0, bA, ks + 2);
#pragma unroll
    for (int mt = 0; mt < 12; ++mt)
      acc[mt] = __builtin_amdgcn_mfma_f32_16x16x32_bf16(a1[mt], bB, acc[mt], 0, 0, 0);
  }
#undef PLOADS
  // D: (kh*4+r) <-> g'-within-tile, rc <-> f-within-wave-slice
  float* zp = zpart + ((size_t)c * ZROWS) * F1 + fh * 128 + w * 16 + rc;
#pragma unroll
  for (int mt = 0; mt < 12; ++mt)
#pragma unroll
    for (int r = 0; r < 4; ++r)
      zp[(size_t)(mt * 16 + kh * 4 + r) * F1] = acc[mt][r];
}

// ---- zpart reduction: z[g][f] = sum_c (hi+lo), p1[g][f] = sum_c ind ----
__global__ void k_zred(const float* __restrict__ zpart, float* __restrict__ z,
                       float* __restrict__ p1) {
  int g = blockIdx.x, q = blockIdx.y, t = threadIdx.x;
  float a = 0.0f, b = 0.0f;
  for (int c = q * 28; c < q * 28 + 28; ++c) {
    const float* base = zpart + (size_t)c * ZROWS * F1;
    a += base[(size_t)g * F1 + t] + base[(size_t)(64 + g) * F1 + t];
    b += base[(size_t)(128 + g) * F1 + t];
  }
  atomicAdd(&z[g * F1 + t], a);
  atomicAdd(&p1[g * F1 + t], b);
}

// ---- final: g = (Z/cnt)@Wl2 + b2 + (P/cnt)@Wr2, then LayerNorm ----
__global__ void k_final(const float* __restrict__ z, const float* __restrict__ p1,
                        const int* __restrict__ cnt,
                        const float* __restrict__ Wl2, const float* __restrict__ b2,
                        const float* __restrict__ Wr2, const float* __restrict__ gamma,
                        const float* __restrict__ beta, float* __restrict__ out) {
  __shared__ float s1[128], s2[128];
  int g = blockIdx.x, j = threadIdx.x;
  float invc = 1.0f / fmaxf((float)cnt[g], 1.0f);
  float acc = 0.0f;
  for (int k = 0; k < 256; ++k) {
    acc += z[g * 256 + k] * Wl2[k * 128 + j] + p1[g * 256 + k] * Wr2[k * 128 + j];
  }
  acc = acc * invc + b2[j];
  s1[j] = acc; s2[j] = acc * acc;
  __syncthreads();
  for (int off = 64; off > 0; off >>= 1) {
    if (j < off) { s1[j] += s1[j + off]; s2[j] += s2[j + off]; }
    __syncthreads();
  }
  float mu = s1[0] / 128.0f;
  float var = s2[0] / 128.0f - mu * mu;
  out[g * 128 + j] = (acc - mu) * rsqrtf(var + 1e-5f) * gamma[j] + beta[j];
}

extern "C" void kernel_launch(void* const* d_in, const int* in_sizes, int n_in,
                              void* d_out, int out_size, void* d_ws, size_t ws_size,
                              hipStream_t stream) {
  const float* x = (const float*)d_in[0];
  const int* ei = (const int*)d_in[1];
  const int* batch = (const int*)d_in[2];
  const float* Wl0 = (const float*)d_in[3];
  const float* b0 = (const float*)d_in[4];
  const float* Wr0 = (const float*)d_in[5];
  const float* Wl1 = (const float*)d_in[6];
  const float* b1 = (const float*)d_in[7];
  const float* Wr1 = (const float*)d_in[8];
  const float* Wl2 = (const float*)d_in[9];
  const float* b2 = (const float*)d_in[10];
  const float* Wr2 = (const float*)d_in[11];
  const float* gamma = (const float*)d_in[12];
  const float* beta = (const float*)d_in[13];
  float* out = (float*)d_out;

  char* p = (char*)d_ws;
  auto alloc = [&](size_t bytes) {
    char* r = p;
    p += (bytes + 511) & ~(size_t)511;
    return r;
  };
  unsigned short* h1T = (unsigned short*)alloc((size_t)F1 * NNP * 2);   // 25.7MB transposed h1
  unsigned short* aggb = (unsigned short*)alloc((size_t)NN * F1 * 2);   // hosts recs+srecs+colx (early), zpart (late)
  float2* axe = (float2*)alloc((size_t)NE * 8);
  int* rowp = (int*)alloc((size_t)(NN + 1) * 4);
  float2* ax = (float2*)alloc((size_t)NN * 8);
  uint2* dg = (uint2*)alloc((size_t)NN * 8);
  int* cnt = (int*)alloc((size_t)NG * 4);
  float* z = (float*)alloc((size_t)NG * F1 * 4);
  float* p1 = (float*)alloc((size_t)NG * F1 * 4);
  unsigned short* wcat = (unsigned short*)alloc((size_t)256 * 512 * 2);
  int* btot_d = (int*)alloc((size_t)NBK * 4);
  int* btot_s = (int*)alloc((size_t)NBS * 4);
  int* bbase = (int*)alloc((size_t)(NBK + 1) * 4);
  int* bcur = (int*)alloc((size_t)NBK * 4);
  int* sbase = (int*)alloc((size_t)(NBS + 1) * 4);
  int* scur = (int*)alloc((size_t)NBS * 4);
  unsigned short* wgT3 = (unsigned short*)alloc((size_t)ZROWS * NNP * 2); // 19.3MB hi/lo/ind bf16
  // Aliasing inside aggb (25.6MB): recs (uint2, 6.4MB @0), srecs (uint, 3.2MB
  // @6.4MB), colx (int, 3.2MB @9.6MB). recs dead after k_csr; srecs dead after
  // k_csc; colx dead after k_axe — all complete before k_agg2 writes aggb.
  // zpart (112*192*256*4 = 22.0MB) aliases aggb after k_gemm1 completes.
  uint2* recs = (uint2*)aggb;
  unsigned int* srecs = (unsigned int*)(aggb + (size_t)NE * 4);
  int* colx = (int*)(aggb + (size_t)NE * 6);
  float* zpart = (float*)aggb;

  hipMemsetAsync(btot_d, 0, (size_t)NBK * 4, stream);
  hipMemsetAsync(btot_s, 0, (size_t)NBS * 4, stream);
  hipMemsetAsync(p1, 0, (size_t)NG * F1 * 4, stream);
  hipMemsetAsync(z, 0, (size_t)NG * F1 * 4, stream);

  k_bhist<<<256, 256, 0, stream>>>(ei, btot_d, btot_s);
  k_bscan<<<1, 512, 0, stream>>>(btot_d, btot_s, bbase, bcur, sbase, scur, rowp);
  k_bscatter<<<SCB, 256, 0, stream>>>(ei, x, bcur, scur, recs, srecs);
  k_csr<<<NBK, 256, 0, stream>>>(recs, bbase, x, batch, rowp, ax, colx, dg);
  k_csc<<<NBS, 256, 0, stream>>>(srecs, sbase, dg, batch, (unsigned int*)wgT3);
  k_cnt<<<1, 64, 0, stream>>>(batch, cnt);
  k_axe<<<(NE + 255) / 256, 256, 0, stream>>>(colx, ax, axe);
  k_wprep<<<(256 * 512 + 255) / 256, 256, 0, stream>>>(Wl1, Wr1, wcat);
  k_agg2<<<2048, 256, 0, stream>>>(axe, rowp, Wl0, b0, Wr0, aggb);
  dim3 gg(392, 2);
  k_gemm1<<<gg, 256, 0, stream>>>(aggb, ax, wcat, Wl0, b0, Wr0, b1, h1T);
  k_poolmm<<<2 * PCHUNKS, 512, 0, stream>>>(h1T, wgT3, zpart);
  dim3 zg(NG, 4);
  k_zred<<<zg, 256, 0, stream>>>(zpart, z, p1);
  k_final<<<NG, 128, 0, stream>>>(z, p1, cnt, Wl2, b2, Wr2, gamma, beta, out);
}